// Round 1
// baseline (110.350 us; speedup 1.0000x reference)
//
#include <hip/hip_runtime.h>

#define BATCH 4
#define SEQ   512
#define DIM   128

// ---------------------------------------------------------------------------
// K0: ep[t][j] = exp(pos_bias[t][j])   (512x512 = 262144 elems)
// ---------------------------------------------------------------------------
__global__ __launch_bounds__(256) void k_exp_pos(const float* __restrict__ pos,
                                                 float* __restrict__ ep) {
    int i = (blockIdx.x * 256 + threadIdx.x) * 4;
    float4 p = *(const float4*)(pos + i);
    float4 r;
    r.x = __expf(p.x);
    r.y = __expf(p.y);
    r.z = __expf(p.z);
    r.w = __expf(p.w);
    *(float4*)(ep + i) = r;
}

// ---------------------------------------------------------------------------
// K1: projections. Each block: 8 rows of x (LDS), 256 threads.
//   col = tid & 127 (output feature e), rg = tid >> 7 selects 4 of the 8 rows.
//   q  = sigmoid(x@Wq^T + bq)
//   ek = exp(x@Wk^T + bk)
//   ekv= ek * (x@Wv^T + bv)
// W reads: thread streams its own W row (f32x4), L1/L2 cached, reused by 8 rows.
// ---------------------------------------------------------------------------
__global__ __launch_bounds__(256) void k_proj(
    const float* __restrict__ x,
    const float* __restrict__ Wq, const float* __restrict__ bq,
    const float* __restrict__ Wk, const float* __restrict__ bk,
    const float* __restrict__ Wv, const float* __restrict__ bv,
    float* __restrict__ q, float* __restrict__ ek, float* __restrict__ ekv)
{
    __shared__ float xs[8 * DIM];  // 4 KB
    const int tid  = threadIdx.x;
    const int row0 = blockIdx.x * 8;

    // cooperative load of 8 x rows (1024 floats = 256 threads x float4)
    *(float4*)(xs + tid * 4) = *(const float4*)(x + row0 * DIM + tid * 4);
    __syncthreads();

    const int col = tid & 127;
    const int rg  = tid >> 7;  // 0 or 1 -> rows rg*4 .. rg*4+3

    float aq[4] = {0.f, 0.f, 0.f, 0.f};
    float ak[4] = {0.f, 0.f, 0.f, 0.f};
    float av[4] = {0.f, 0.f, 0.f, 0.f};

    const float4* wq4 = (const float4*)(Wq + col * DIM);
    const float4* wk4 = (const float4*)(Wk + col * DIM);
    const float4* wv4 = (const float4*)(Wv + col * DIM);

    for (int d4 = 0; d4 < DIM / 4; ++d4) {
        const float4 wq = wq4[d4];
        const float4 wk = wk4[d4];
        const float4 wv = wv4[d4];
#pragma unroll
        for (int r = 0; r < 4; ++r) {
            const float4 xv = *(const float4*)(xs + (rg * 4 + r) * DIM + d4 * 4);
            aq[r] = fmaf(xv.x, wq.x, fmaf(xv.y, wq.y, fmaf(xv.z, wq.z, fmaf(xv.w, wq.w, aq[r]))));
            ak[r] = fmaf(xv.x, wk.x, fmaf(xv.y, wk.y, fmaf(xv.z, wk.z, fmaf(xv.w, wk.w, ak[r]))));
            av[r] = fmaf(xv.x, wv.x, fmaf(xv.y, wv.y, fmaf(xv.z, wv.z, fmaf(xv.w, wv.w, av[r]))));
        }
    }

    const float bqv = bq[col];
    const float bkv = bk[col];
    const float bvv = bv[col];
#pragma unroll
    for (int r = 0; r < 4; ++r) {
        const int row = row0 + rg * 4 + r;
        const float kk = ak[r] + bkv;
        const float e  = __expf(kk);
        const float vv = av[r] + bvv;
        const float qq = 1.f / (1.f + __expf(-(aq[r] + bqv)));
        q[row * DIM + col]   = qq;
        ek[row * DIM + col]  = e;
        ekv[row * DIM + col] = e * vv;
    }
}

// ---------------------------------------------------------------------------
// K2: AFT core.
//   num[b,t,d] = sum_j ep[t,j] * ekv[b,j,d]
//   den[b,t,d] = sum_j ep[t,j] * ek [b,j,d]
//   out        = q * num / den
// Grid: 256 blocks = (b:4) x (t-tile:16 of 32) x (d-tile:4 of 32).
// Block: 256 threads; thread = (tt = tid>>3 in [0,32), dg = tid&7) computes
// 1 t x 4 d outputs, j-loop staged through LDS in chunks of 64.
// ep_s padded to 68 floats/row: 8 distinct tt addresses land in 8 distinct
// banks (stride 68 % 32 = 4), same-tt lanes broadcast.
// ---------------------------------------------------------------------------
__global__ __launch_bounds__(256) void k_aft(
    const float* __restrict__ ep,
    const float* __restrict__ ek,
    const float* __restrict__ ekv,
    const float* __restrict__ q,
    float* __restrict__ out)
{
    __shared__ float ep_s[32][68];
    __shared__ float ek_s[64][32];
    __shared__ float ekv_s[64][32];

    const int bi = blockIdx.x;
    const int b  = bi >> 6;
    const int t0 = ((bi >> 2) & 15) * 32;
    const int d0 = (bi & 3) * 32;

    const int tid = threadIdx.x;
    const int tt  = tid >> 3;  // 0..31
    const int dg  = tid & 7;   // 0..7 (4 d's each)

    const float* ekb  = ek  + b * SEQ * DIM;
    const float* ekvb = ekv + b * SEQ * DIM;

    float num[4] = {0.f, 0.f, 0.f, 0.f};
    float den[4] = {0.f, 0.f, 0.f, 0.f};

    for (int j0 = 0; j0 < SEQ; j0 += 64) {
        // stage ep tile [32t x 64j]: 2 float4 per thread
        {
            const int r  = tid >> 3;
            const int c4 = (tid & 7) * 4;
            *(float4*)(&ep_s[r][c4])      = *(const float4*)(ep + (t0 + r) * SEQ + j0 + c4);
            *(float4*)(&ep_s[r][32 + c4]) = *(const float4*)(ep + (t0 + r) * SEQ + j0 + 32 + c4);
        }
        // stage ek/ekv tiles [64j x 32d]: 2 rows per thread each
        {
            const int r  = tid >> 3;
            const int c4 = (tid & 7) * 4;
            *(float4*)(&ek_s[r][c4])       = *(const float4*)(ekb  + (j0 + r) * DIM + d0 + c4);
            *(float4*)(&ek_s[r + 32][c4])  = *(const float4*)(ekb  + (j0 + r + 32) * DIM + d0 + c4);
            *(float4*)(&ekv_s[r][c4])      = *(const float4*)(ekvb + (j0 + r) * DIM + d0 + c4);
            *(float4*)(&ekv_s[r + 32][c4]) = *(const float4*)(ekvb + (j0 + r + 32) * DIM + d0 + c4);
        }
        __syncthreads();

#pragma unroll 8
        for (int jj = 0; jj < 64; ++jj) {
            const float  w  = ep_s[tt][jj];
            const float4 e4 = *(const float4*)(&ek_s[jj][dg * 4]);
            const float4 v4 = *(const float4*)(&ekv_s[jj][dg * 4]);
            den[0] = fmaf(w, e4.x, den[0]);
            den[1] = fmaf(w, e4.y, den[1]);
            den[2] = fmaf(w, e4.z, den[2]);
            den[3] = fmaf(w, e4.w, den[3]);
            num[0] = fmaf(w, v4.x, num[0]);
            num[1] = fmaf(w, v4.y, num[1]);
            num[2] = fmaf(w, v4.z, num[2]);
            num[3] = fmaf(w, v4.w, num[3]);
        }
        __syncthreads();
    }

    const int t  = t0 + tt;
    const int di = d0 + dg * 4;
    const float4 q4 = *(const float4*)(q + (b * SEQ + t) * DIM + di);
    float4 o;
    o.x = q4.x * num[0] / den[0];
    o.y = q4.y * num[1] / den[1];
    o.z = q4.z * num[2] / den[2];
    o.w = q4.w * num[3] / den[3];
    *(float4*)(out + (b * SEQ + t) * DIM + di) = o;
}

// ---------------------------------------------------------------------------
extern "C" void kernel_launch(void* const* d_in, const int* in_sizes, int n_in,
                              void* d_out, int out_size, void* d_ws, size_t ws_size,
                              hipStream_t stream) {
    const float* x   = (const float*)d_in[0];
    const float* Wq  = (const float*)d_in[1];
    const float* bq  = (const float*)d_in[2];
    const float* Wk  = (const float*)d_in[3];
    const float* bk  = (const float*)d_in[4];
    const float* Wv  = (const float*)d_in[5];
    const float* bv  = (const float*)d_in[6];
    const float* pos = (const float*)d_in[7];

    float* outp = (float*)d_out;
    float* ws   = (float*)d_ws;

    float* q   = ws;                 // 262144 floats
    float* ek  = ws + 262144;        // 262144
    float* ekv = ws + 524288;        // 262144
    float* ep  = ws + 786432;        // 262144  (total 4 MB)

    k_exp_pos<<<256, 256, 0, stream>>>(pos, ep);
    k_proj<<<BATCH * SEQ / 8, 256, 0, stream>>>(x, Wq, bq, Wk, bk, Wv, bv, q, ek, ekv);
    k_aft<<<256, 256, 0, stream>>>(ep, ek, ekv, q, outp);
}

// Round 2
// 80.374 us; speedup vs baseline: 1.3730x; 1.3730x over previous
//
#include <hip/hip_runtime.h>

#define BATCH 4
#define SEQ   512
#define DIM   128

typedef _Float16 half8 __attribute__((ext_vector_type(8)));
typedef _Float16 half4 __attribute__((ext_vector_type(4)));
typedef float    f32x4 __attribute__((ext_vector_type(4)));

// ---------------------------------------------------------------------------
// K0 prep: f32 -> f16 conversions.
//   blocks [0,128)   : x      (262144)          -> x_h
//   blocks [128,256) : pos    (262144), exp()   -> ep_h
//   blocks [256,280) : Wq/Wk/Wv (16384 each)    -> wq_h/wk_h/wv_h
// ---------------------------------------------------------------------------
__global__ __launch_bounds__(256) void k_prep(
    const float* __restrict__ x, const float* __restrict__ pos,
    const float* __restrict__ Wq, const float* __restrict__ Wk,
    const float* __restrict__ Wv,
    _Float16* __restrict__ x_h, _Float16* __restrict__ ep_h,
    _Float16* __restrict__ wq_h, _Float16* __restrict__ wk_h,
    _Float16* __restrict__ wv_h)
{
    const int blk = blockIdx.x;
    const int tid = threadIdx.x;
    if (blk < 128) {
        const int i = (blk * 256 + tid) * 8;
        const float4 p0 = *(const float4*)(x + i);
        const float4 p1 = *(const float4*)(x + i + 4);
        half8 h;
        h[0]=(_Float16)p0.x; h[1]=(_Float16)p0.y; h[2]=(_Float16)p0.z; h[3]=(_Float16)p0.w;
        h[4]=(_Float16)p1.x; h[5]=(_Float16)p1.y; h[6]=(_Float16)p1.z; h[7]=(_Float16)p1.w;
        *(half8*)(x_h + i) = h;
    } else if (blk < 256) {
        const int i = ((blk - 128) * 256 + tid) * 8;
        const float4 p0 = *(const float4*)(pos + i);
        const float4 p1 = *(const float4*)(pos + i + 4);
        half8 h;
        h[0]=(_Float16)__expf(p0.x); h[1]=(_Float16)__expf(p0.y);
        h[2]=(_Float16)__expf(p0.z); h[3]=(_Float16)__expf(p0.w);
        h[4]=(_Float16)__expf(p1.x); h[5]=(_Float16)__expf(p1.y);
        h[6]=(_Float16)__expf(p1.z); h[7]=(_Float16)__expf(p1.w);
        *(half8*)(ep_h + i) = h;
    } else {
        const int r = blk - 256;                  // 0..23
        const float* src = (r < 8) ? Wq : ((r < 16) ? Wk : Wv);
        _Float16* dst    = (r < 8) ? wq_h : ((r < 16) ? wk_h : wv_h);
        const int i = ((r & 7) * 256 + tid) * 8;
        const float4 p0 = *(const float4*)(src + i);
        const float4 p1 = *(const float4*)(src + i + 4);
        half8 h;
        h[0]=(_Float16)p0.x; h[1]=(_Float16)p0.y; h[2]=(_Float16)p0.z; h[3]=(_Float16)p0.w;
        h[4]=(_Float16)p1.x; h[5]=(_Float16)p1.y; h[6]=(_Float16)p1.z; h[7]=(_Float16)p1.w;
        *(half8*)(dst + i) = h;
    }
}

// ---------------------------------------------------------------------------
// K1 proj (MFMA): D[token][col] = x @ W^T for q,k,v simultaneously.
// Wave tile 16m(token) x 16n(col), all three matrices in the same lane so the
// exp(k)*v fusion is local. Block = 4 waves stacked in m (64 tokens x 16 cols).
// Grid = (2048/64 m-blocks) x (128/16 n-blocks) = 32 x 8 = 256 blocks.
// Epilogue:
//   q[b][tok][col]            = sigmoid(dq + bq)   (f32, natural layout)
//   ekk[b][2c+0][tok] (f16)   = exp(dk + bk)              (den operand)
//   ekk[b][2c+1][tok] (f16)   = exp(dk + bk)*(dv + bv)    (num operand)
// ---------------------------------------------------------------------------
__global__ __launch_bounds__(256) void k_proj(
    const _Float16* __restrict__ x_h,
    const _Float16* __restrict__ wq_h, const float* __restrict__ bq,
    const _Float16* __restrict__ wk_h, const float* __restrict__ bk,
    const _Float16* __restrict__ wv_h, const float* __restrict__ bv,
    float* __restrict__ qout, _Float16* __restrict__ ekk)
{
    const int tid  = threadIdx.x;
    const int lane = tid & 63;
    const int wave = tid >> 6;
    const int l15  = lane & 15;
    const int quad = lane >> 4;

    const int n0 = (blockIdx.x & 7) * 16;               // col tile
    const int m0 = (blockIdx.x >> 3) * 64 + wave * 16;  // token-row tile

    const _Float16* xa = x_h  + (m0 + l15) * DIM + quad * 8;
    const _Float16* wq = wq_h + (n0 + l15) * DIM + quad * 8;
    const _Float16* wk = wk_h + (n0 + l15) * DIM + quad * 8;
    const _Float16* wv = wv_h + (n0 + l15) * DIM + quad * 8;

    f32x4 aq = {0.f, 0.f, 0.f, 0.f};
    f32x4 ak = {0.f, 0.f, 0.f, 0.f};
    f32x4 av = {0.f, 0.f, 0.f, 0.f};

#pragma unroll
    for (int ks = 0; ks < 4; ++ks) {            // K = 128, 32 per step
        const half8 a  = *(const half8*)(xa + ks * 32);
        const half8 b0 = *(const half8*)(wq + ks * 32);
        const half8 b1 = *(const half8*)(wk + ks * 32);
        const half8 b2 = *(const half8*)(wv + ks * 32);
        aq = __builtin_amdgcn_mfma_f32_16x16x32_f16(a, b0, aq, 0, 0, 0);
        ak = __builtin_amdgcn_mfma_f32_16x16x32_f16(a, b1, ak, 0, 0, 0);
        av = __builtin_amdgcn_mfma_f32_16x16x32_f16(a, b2, av, 0, 0, 0);
    }

    const int c   = n0 + l15;
    const float bqv = bq[c];
    const float bkv = bk[c];
    const float bvv = bv[c];

    const int mrow = m0 + quad * 4;   // first of 4 token rows this lane holds
    const int b    = mrow >> 9;       // /512 (all 4 rows same batch)
    const int tok  = mrow & 511;

    half4 eh, evh;
#pragma unroll
    for (int r = 0; r < 4; ++r) {
        const float e  = __expf(ak[r] + bkv);
        const float vv = av[r] + bvv;
        const float qv = 1.f / (1.f + __expf(-(aq[r] + bqv)));
        eh[r]  = (_Float16)e;
        evh[r] = (_Float16)(e * vv);
        qout[(b * SEQ + tok + r) * DIM + c] = qv;
    }
    *(half4*)(ekk + ((b * 256) + 2 * c + 0) * SEQ + tok) = eh;
    *(half4*)(ekk + ((b * 256) + 2 * c + 1) * SEQ + tok) = evh;
}

// ---------------------------------------------------------------------------
// K2 AFT (MFMA, zero LDS): per b, D[m][t] = sum_j ekk[m][j] * ep[t][j]
//   m in [0,256): even rows = den (ek), odd rows = num (ekv), interleaved so
//   each lane's 4 accumulator regs hold (den,num) for 2 consecutive d.
// Wave tile 16m x 32t (2 MFMAs/k-step); block = 4 waves (2m x 2t) = 32m x 64t.
// Grid = 4b x (256/32) x (512/64) = 256 blocks. Operands are direct 16B
// global loads (L2-resident, ~3 MB working set). K=512 -> 16 steps.
// Epilogue: out[b][t][d] = q[b][t][d] * num/den.
// ---------------------------------------------------------------------------
__global__ __launch_bounds__(256) void k_aft(
    const _Float16* __restrict__ ekk,
    const _Float16* __restrict__ ep_h,
    const float* __restrict__ qout,
    float* __restrict__ out)
{
    const int tid  = threadIdx.x;
    const int lane = tid & 63;
    const int wave = tid >> 6;
    const int l15  = lane & 15;
    const int quad = lane >> 4;
    const int wm   = wave & 1;
    const int wn   = wave >> 1;

    const int b  = blockIdx.x >> 6;
    const int m0 = (((blockIdx.x >> 3) & 7) * 32) + wm * 16;  // [0,256)
    const int t0 = ((blockIdx.x & 7) * 64) + wn * 32;         // [0,512)

    const _Float16* arow  = ekk  + ((b * 256) + m0 + l15) * SEQ + quad * 8;
    const _Float16* brow0 = ep_h + (t0 + l15) * SEQ + quad * 8;
    const _Float16* brow1 = brow0 + 16 * SEQ;

    f32x4 acc0 = {0.f, 0.f, 0.f, 0.f};
    f32x4 acc1 = {0.f, 0.f, 0.f, 0.f};

#pragma unroll
    for (int ks = 0; ks < 16; ++ks) {           // K = 512, 32 per step
        const half8 a  = *(const half8*)(arow  + ks * 32);
        const half8 b0 = *(const half8*)(brow0 + ks * 32);
        const half8 b1 = *(const half8*)(brow1 + ks * 32);
        acc0 = __builtin_amdgcn_mfma_f32_16x16x32_f16(a, b0, acc0, 0, 0, 0);
        acc1 = __builtin_amdgcn_mfma_f32_16x16x32_f16(a, b1, acc1, 0, 0, 0);
    }

    // lane holds rows m0+quad*4+{0..3} = (den,num) for d0 and d0+1
    const int d0 = (m0 + quad * 4) >> 1;   // even
#pragma unroll
    for (int i = 0; i < 2; ++i) {
        const f32x4 acc = i ? acc1 : acc0;
        const int t = t0 + i * 16 + l15;
        const float2 qv = *(const float2*)(qout + ((b * SEQ) + t) * DIM + d0);
        float2 o;
        o.x = qv.x * acc[1] / acc[0];
        o.y = qv.y * acc[3] / acc[2];
        *(float2*)(out + ((b * SEQ) + t) * DIM + d0) = o;
    }
}

// ---------------------------------------------------------------------------
extern "C" void kernel_launch(void* const* d_in, const int* in_sizes, int n_in,
                              void* d_out, int out_size, void* d_ws, size_t ws_size,
                              hipStream_t stream) {
    const float* x   = (const float*)d_in[0];
    const float* Wq  = (const float*)d_in[1];
    const float* bq  = (const float*)d_in[2];
    const float* Wk  = (const float*)d_in[3];
    const float* bk  = (const float*)d_in[4];
    const float* Wv  = (const float*)d_in[5];
    const float* bv  = (const float*)d_in[6];
    const float* pos = (const float*)d_in[7];

    float* outp = (float*)d_out;
    char*  ws   = (char*)d_ws;

    _Float16* x_h  = (_Float16*)(ws);                       // 512 KB
    _Float16* ep_h = (_Float16*)(ws + (512 << 10));         // 512 KB
    _Float16* ekk  = (_Float16*)(ws + (1024 << 10));        // 1 MB
    _Float16* wq_h = (_Float16*)(ws + (2048 << 10));        // 32 KB
    _Float16* wk_h = (_Float16*)(ws + (2080 << 10));        // 32 KB
    _Float16* wv_h = (_Float16*)(ws + (2112 << 10));        // 32 KB
    float*    qout = (float*)   (ws + (2144 << 10));        // 1 MB

    k_prep<<<280, 256, 0, stream>>>(x, pos, Wq, Wk, Wv, x_h, ep_h, wq_h, wk_h, wv_h);
    k_proj<<<256, 256, 0, stream>>>(x_h, wq_h, bq, wk_h, bk, wv_h, bv, qout, ekk);
    k_aft<<<256, 256, 0, stream>>>(ekk, ep_h, qout, outp);
}